// Round 2
// baseline (170662.830 us; speedup 1.0000x reference)
//
#include <hip/hip_runtime.h>
#include <stdint.h>

#define HW 16384
#define NI 64
#define NM 256
#define WORDS 256

// plane padding: stride 136 floats/row (4 guard cols each side, zeroed)
#define PR 136
#define PSZ (26 * PR)   // 3536 floats per plane
// state padding: stride 34 words/row (1 guard word each side, zeroed)
#define SR 34

// ws layout
#define OFF_STATE2 (1u << 20)    // 1 MB state bytes (halo exchange)
#define OFF_PACKED (2u << 20)    // 512 KB bit-packed masks [word][mask]
#define OFF_DIOUT  0x280000u     // 256 KB diou transposed diouT[col][row]
#define OFF_COMPM  0x2C0000u
#define OFF_CNT    0x2C1000u     // 64 counters (+ ticket slot for fallback)
#define OFF_BAR    0x2C1800u     // bar[0]=cnt bar[1]=gen bar[2]=fail flag
#define OFF_GPLANE 0x300000u     // 27.3 MB plane spill (fallback path only)

// ---------------------------------------------------------------------------
// Barrier-state init (graph-capturable; runs each launch so replay is clean).
// ---------------------------------------------------------------------------
__global__ void init_kernel(int* __restrict__ bar) {
    if (threadIdx.x < 4) bar[threadIdx.x] = 0;
}

// ---------------------------------------------------------------------------
// Manual device-scope grid barrier (__ockl_grid_sync pattern). Safe because
// grid=512 == 2 blocks/CU x 256 CUs and LDS (63.7KB) caps occupancy at
// exactly 2/CU -> all blocks co-resident by construction. clock64 valve sets
// bar[2] instead of hanging; guarded fallback pipeline then recomputes.
// ---------------------------------------------------------------------------
__device__ __forceinline__ void grid_barrier(int* __restrict__ bar, const int tid) {
    __threadfence();               // release: make this block's stores visible
    __syncthreads();
    if (tid == 0) {
        int g = __hip_atomic_load(bar + 1, __ATOMIC_RELAXED, __HIP_MEMORY_SCOPE_AGENT);
        if (__hip_atomic_fetch_add(bar, 1, __ATOMIC_ACQ_REL, __HIP_MEMORY_SCOPE_AGENT) == 511) {
            __hip_atomic_store(bar, 0, __ATOMIC_RELAXED, __HIP_MEMORY_SCOPE_AGENT);
            __hip_atomic_fetch_add(bar + 1, 1, __ATOMIC_ACQ_REL, __HIP_MEMORY_SCOPE_AGENT);
        } else {
            const long long t0 = clock64();
            while (__hip_atomic_load(bar + 1, __ATOMIC_RELAXED, __HIP_MEMORY_SCOPE_AGENT) == g) {
                __builtin_amdgcn_s_sleep(10);
                if (clock64() - t0 > 200000000LL) {  // ~80 ms valve
                    __hip_atomic_store(bar + 2, 1, __ATOMIC_RELAXED, __HIP_MEMORY_SCOPE_AGENT);
                    break;
                }
            }
        }
    }
    __syncthreads();
    __threadfence();               // acquire: see other blocks' stores
}

// ---------------------------------------------------------------------------
// 5-sweep CRF body — R13-proven math, verbatim. Memo state (pin/powv/haveprev)
// and buffer parity (cur) persist across the two calls inside the fused
// kernel (value-exact memoization: identical 9-word inputs -> identical word).
// ---------------------------------------------------------------------------
__device__ __forceinline__ int sweeps5(
    const float* __restrict__ plane, uint32_t (&stw)[2][26 * SR],
    int* __restrict__ chg, const int tid, const int r0, const int y,
    const bool compute, const int rbase, const int sbase, int cur,
    uint32_t (&pin)[9], uint32_t& powv, bool& haveprev) {
    #pragma clang fp contract(off)
    const float l45 = 0.7985076962177716f;  // -log(0.45f)
    const float l55 = 0.5978370007556204f;  // -log(0.55f)
    const int lane = tid & 63;
    for (int s = 0; s < 5; ++s) {
        if (tid == 0) *chg = 0;
        __syncthreads();
        const int lo = (r0 - 4 + s < 0) ? 0 : r0 - 4 + s;
        const int hi = (r0 + 20 - s > 128) ? 128 : r0 + 20 - s;
        const bool act = compute && (y >= lo) && (y < hi);
        bool changed = false;
        if (act) {
            const uint32_t* sw = &stw[cur][0];
            uint32_t in9[9];
            #pragma unroll
            for (int r = 0; r < 3; ++r) {
                const int base = sbase + (r - 1) * SR;
                in9[r * 3 + 0] = sw[base - 1];
                in9[r * 3 + 1] = sw[base];
                in9[r * 3 + 2] = sw[base + 1];
            }
            const uint32_t wcen = in9[4];
            bool same = haveprev;
            #pragma unroll
            for (int m = 0; m < 9; ++m) same = same && (in9[m] == pin[m]);
            uint32_t ow;
            if (same) {
                ow = powv;  // deterministic map on identical inputs — exact
            } else {
                float lx1r[3][6], lx0r[3][6];
                #pragma unroll
                for (int r = 0; r < 3; ++r) {
                    const uint32_t wm = in9[r * 3 + 0];
                    const uint32_t wc = in9[r * 3 + 1];
                    const uint32_t wp = in9[r * 3 + 2];
                    unsigned char b[6];
                    b[0] = wm >> 24;
                    b[1] = wc & 0xff; b[2] = (wc >> 8) & 0xff;
                    b[3] = (wc >> 16) & 0xff; b[4] = wc >> 24;
                    b[5] = wp & 0xff;
                    #pragma unroll
                    for (int m = 0; m < 6; ++m) {
                        lx1r[r][m] = (b[m] & 1) ? l55 : l45;
                        lx0r[r][m] = (b[m] & 2) ? l55 : l45;
                    }
                }
                // kw gather: 7 x b128 + 3 scalars via mirror identity
                float4 p0a = *(const float4*)&plane[0 * PSZ + rbase];
                float4 p1a = *(const float4*)&plane[1 * PSZ + rbase];
                float4 p2a = *(const float4*)&plane[2 * PSZ + rbase];
                float4 p3a = *(const float4*)&plane[3 * PSZ + rbase];
                float4 p0b = *(const float4*)&plane[0 * PSZ + rbase + PR];
                float4 p1b = *(const float4*)&plane[1 * PSZ + rbase + PR];
                float4 p2b = *(const float4*)&plane[2 * PSZ + rbase + PR];
                float s5 = plane[3 * PSZ + rbase + 4];
                float s6 = plane[2 * PSZ + rbase + PR - 1];
                float s8 = plane[0 * PSZ + rbase + PR + 4];
                const float kw[9][4] = {
                    {p0a.x, p0a.y, p0a.z, p0a.w},
                    {p1a.x, p1a.y, p1a.z, p1a.w},
                    {p2a.x, p2a.y, p2a.z, p2a.w},
                    {p3a.x, p3a.y, p3a.z, p3a.w},
                    {3.0f, 3.0f, 3.0f, 3.0f},
                    {p3a.y, p3a.z, p3a.w, s5},
                    {s6, p2b.x, p2b.y, p2b.z},
                    {p1b.x, p1b.y, p1b.z, p1b.w},
                    {p0b.y, p0b.z, p0b.w, s8}};
                float a0[4] = {0.f, 0.f, 0.f, 0.f}, a1[4] = {0.f, 0.f, 0.f, 0.f};
                #pragma unroll
                for (int k = 0; k < 9; ++k) {
                    const int r = k / 3, m0 = k % 3;
                    #pragma unroll
                    for (int j = 0; j < 4; ++j) {
                        const float kwv = kw[k][j];
                        const float t1 = lx1r[r][j + m0] * kwv;  // mul then add
                        const float t0 = lx0r[r][j + m0] * kwv;
                        a1[j] = a1[j] + t1;
                        a0[j] = a0[j] + t0;
                    }
                }
                // epilogue (proven exact sequence)
                ow = 0;
                #pragma unroll
                for (int j = 0; j < 4; ++j) {
                    const unsigned char sc = (wcen >> (8 * j)) & 0xffu;
                    const float tval = (sc & 4) ? 1.0f : 0.0f;
                    const float e1 = expf(-a1[j]);
                    const float e0 = expf(-a0[j]);
                    const float m1 = e1 * tval;
                    const float f1 = m1 + 1e-6f;
                    const float f0 = e0 + 1e-6f;
                    const float den = f0 + f1;
                    const float r1 = f1 / den;
                    const float r0v = f0 / den;
                    const int s1 = (r1 > 0.5f) ? 1 : 0;
                    const int s0 = (r0v > 0.5f) ? 1 : 0;
                    ow |= (uint32_t)(s1 | (s0 << 1) | (sc & 4)) << (8 * j);
                }
                #pragma unroll
                for (int m = 0; m < 9; ++m) pin[m] = in9[m];
                powv = ow;
                haveprev = true;
            }
            stw[cur ^ 1][sbase] = ow;
            changed = (ow != wcen);
        }
        unsigned long long bal = __ballot(changed);
        if (lane == 0 && bal) atomicOr(chg, 1);
        __syncthreads();
        if (*chg == 0) break;  // fixed point: all later sweeps identical (exact)
        cur ^= 1;
    }
    return cur;
}

// ---------------------------------------------------------------------------
// Fused kernel (regular launch, manual grid barriers):
// pack + planes + iters 1-5 | bar | diou/compm + halo restage + iters 6-10 +
// masks/counts | bar | coef + valid. Planes, state LDS, and memo registers
// persist across the barriers -> no gplane spill/reload, warm memo at iter 6.
// ---------------------------------------------------------------------------
__global__ __launch_bounds__(832, 6) void fused_kernel(
    const float* __restrict__ feat, const float* __restrict__ scores,
    float* __restrict__ diouT, float* __restrict__ compm,
    const float* __restrict__ seg, unsigned long long* __restrict__ packed,
    const int* __restrict__ labels, const float* __restrict__ x,
    const float* __restrict__ targets, unsigned char* __restrict__ state2,
    float* __restrict__ out, int* __restrict__ counters, int* __restrict__ bar) {
    #pragma clang fp contract(off)
    __shared__ float plane[4 * PSZ];      // 56576 B
    __shared__ uint32_t stw[2][26 * SR];  // 7072 B
    __shared__ int chg;
    __shared__ float dred[4];             // total 63668 B < 64 KiB -> 2 blk/CU
    const int tid = threadIdx.x, bid = blockIdx.x;
    const int img = bid >> 3, r0 = (bid & 7) * 16;
    const int w0 = r0 - 5;
    const int rel = tid >> 5;             // 0..25
    const int q = tid & 31;
    const int xc = q * 4;
    const int y = w0 + rel;
    const bool inimg = (unsigned)y < 128u;

    // ---- Phase 1a: pack, balanced over ALL 6656 waves ----------------------
    {
        const int wave = tid >> 6, lane = tid & 63;
        const int gw = bid * 13 + wave;          // 0..6655
        for (int gwi = gw; gwi < 65536; gwi += 6656) {
            const int i = gwi >> 8, w = gwi & 255;
            float v = seg[(size_t)i * HW + w * 64 + lane];
            unsigned long long m = __ballot(v > 0.5f);
            if (lane == 0) packed[w * NM + i] = m;
        }
        if (bid == 0 && tid < NI) counters[tid] = 0;
    }

    // ---- Phase 1b: planes -> LDS (proven sequence; NO gplane spill) --------
    {
        const float* fb = feat + (size_t)img * 3 * HW;
        float c0[4], c1[4], c2[4];
        if (inimg) {
            const int pp = y * 128 + xc;
            float4 cv0 = *(const float4*)&fb[pp];
            float4 cv1 = *(const float4*)&fb[HW + pp];
            float4 cv2 = *(const float4*)&fb[2 * HW + pp];
            c0[0]=cv0.x+10.0f; c0[1]=cv0.y+10.0f; c0[2]=cv0.z+10.0f; c0[3]=cv0.w+10.0f;
            c1[0]=cv1.x+10.0f; c1[1]=cv1.y+10.0f; c1[2]=cv1.z+10.0f; c1[3]=cv1.w+10.0f;
            c2[0]=cv2.x+10.0f; c2[1]=cv2.y+10.0f; c2[2]=cv2.z+10.0f; c2[3]=cv2.w+10.0f;
        }
        #pragma unroll
        for (int k = 0; k < 4; ++k) {
            const int dy = (k < 3) ? -1 : 0;
            const int dx = (k < 3) ? (k - 1) : -1;
            float res[4] = {0.0f, 0.0f, 0.0f, 0.0f};
            if (inimg) {
                const int ny = y + dy;
                if ((unsigned)ny < 128u) {
                    #pragma unroll
                    for (int j = 0; j < 4; ++j) {
                        const int nx = xc + j + dx;
                        if ((unsigned)nx < 128u) {
                            const int qq = ny * 128 + nx;
                            float u0 = fb[qq] + 10.0f;
                            float u1 = fb[HW + qq] + 10.0f;
                            float u2 = fb[2 * HW + qq] + 10.0f;
                            float d0 = u0 - c0[j], d1 = u1 - c1[j], d2 = u2 - c2[j];
                            float ss = d0 * d0;
                            ss = ss + d1 * d1;
                            ss = ss + d2 * d2;
                            float color = (-ss) / 0.5f;
                            float sp = (float)(dy * dy + dx * dx) / 1800.0f;
                            res[j] = 3.0f * expf(color - sp);
                        }
                    }
                }
            }
            *(float4*)&plane[k * PSZ + rel * PR + 4 + xc] =
                make_float4(res[0], res[1], res[2], res[3]);
            if (q == 0)
                *(float4*)&plane[k * PSZ + rel * PR + 0] = make_float4(0, 0, 0, 0);
            if (q == 31)
                *(float4*)&plane[k * PSZ + rel * PR + 132] = make_float4(0, 0, 0, 0);
        }
    }

    // ---- Phase 1c: state init from x,targets (proven) ----------------------
    {
        uint32_t st = 0;
        if (inimg) {
            const size_t gp = (size_t)img * HW + y * 128 + xc;
            const float4 xv = *(const float4*)(x + gp);
            const float4 tv = *(const float4*)(targets + gp);
            float xs[4] = {xv.x, xv.y, xv.z, xv.w};
            float ts[4] = {tv.x, tv.y, tv.z, tv.w};
            #pragma unroll
            for (int j = 0; j < 4; ++j) {
                float xt = xs[j] * ts[j];
                int b1 = (xt > 0.5f) ? 1 : 0;
                int tb = (ts[j] > 0.5f) ? 1 : 0;
                st |= (uint32_t)(b1 | ((b1 ^ 1) << 1) | (tb << 2)) << (8 * j);
            }
        }
        stw[0][rel * SR + 1 + q] = st;
        if (!inimg) stw[1][rel * SR + 1 + q] = 0;
        if (q == 0)  { stw[0][rel * SR + 0]  = 0; stw[1][rel * SR + 0]  = 0; }
        if (q == 31) { stw[0][rel * SR + 33] = 0; stw[1][rel * SR + 33] = 0; }
    }
    __syncthreads();

    const bool compute = inimg && (y >= r0 - 4) && (y < r0 + 20);
    const int rbase = rel * PR + 4 + xc;
    const int sbase = rel * SR + 1 + q;
    uint32_t pin[9];
    uint32_t powv = 0;
    bool haveprev = false;

    // ---- CRF iters 1-5 -----------------------------------------------------
    int cur = sweeps5(plane, stw, &chg, tid, r0, y, compute, rbase, sbase, 0,
                      pin, powv, haveprev);

    // ---- own rows -> state2 (halo exchange) --------------------------------
    if (inimg && y >= r0 && y < r0 + 16)
        ((uint32_t*)(state2 + (size_t)img * HW))[y * 32 + q] = stw[cur][sbase];

    grid_barrier(bar, tid);  // packed + state2 now globally visible

    // ---- Phase 2a: diou + compm on blocks 256..511 (LDS-free) --------------
    // fmaxf is exactly associative -> shfl butterfly == proven LDS tree.
    if (bid >= NM) {
        const int j = bid - NM;
        if (tid < NM) {
            int inter = 0, si = 0, sj = 0;
            for (int w = 0; w < WORDS; ++w) {
                unsigned long long a = packed[w * NM + j];    // uniform
                unsigned long long b = packed[w * NM + tid];
                inter += __popcll(a & b);
                sj += __popcll(a);
                si += __popcll(b);
            }
            float d = 0.0f;
            if (j > tid && labels[tid] == labels[j]) {
                float u = (float)(si + sj - inter);   // exact integers in f32
                d = (float)inter / u;
            }
            diouT[j * NM + tid] = d;
            float m = d;
            #pragma unroll
            for (int off = 1; off < 64; off <<= 1) m = fmaxf(m, __shfl_xor(m, off));
            if ((tid & 63) == 0) dred[tid >> 6] = m;
        }
        __syncthreads();
        if (tid == 0) {
            float m = fmaxf(fmaxf(dred[0], dred[1]), fmaxf(dred[2], dred[3]));
            float t = m * m;
            compm[j] = expf(-2.0f * t);
        }
    }

    // ---- Phase 2b: halo-only restage (own 16 rows persist in stw[cur]) -----
    if (inimg && (rel < 5 || rel >= 21))
        stw[cur][sbase] =
            ((const uint32_t*)(state2 + (size_t)img * HW + y * 128))[q];
    __syncthreads();

    // ---- CRF iters 6-10 (planes + memo persist: sweep 6 mostly memo-hits) --
    cur = sweeps5(plane, stw, &chg, tid, r0, y, compute, rbase, sbase, cur,
                  pin, powv, haveprev);

    // ---- emission: masks + per-image counts --------------------------------
    int cnt = 0;
    if (inimg && y >= r0 && y < r0 + 16) {
        const uint32_t w = stw[cur][sbase];
        float* om = out + NM + (size_t)img * HW;
        *(float4*)(om + y * 128 + xc) =
            make_float4((float)(w & 1), (float)((w >> 8) & 1),
                        (float)((w >> 16) & 1), (float)((w >> 24) & 1));
        cnt = __popc(w & 0x01010101u);
    }
    __syncthreads();   // before plane reuse as cred
    {
        int* cred = (int*)plane;
        cred[tid] = cnt;
        if (tid < 192) cred[832 + tid] = 0;   // pad to 1024
        __syncthreads();
        for (int off = 512; off > 0; off >>= 1) {
            if (tid < off) cred[tid] += cred[tid + off];
            __syncthreads();
        }
        if (tid == 0) atomicAdd(&counters[img], cred[0]);
    }

    grid_barrier(bar, tid);  // diouT/compm/counters final

    // ---- Phase 3: coef (proven prologue, verbatim) + valid -----------------
    if (bid < NM) {
        float* red = plane;
        if (tid < NM) {
            float d = diouT[bid * NM + tid];
            float dd = d * d;
            float dec = expf(-2.0f * dd);
            red[tid] = dec / compm[tid];
        }
        __syncthreads();
        for (int off = 128; off > 0; off >>= 1) {
            if (tid < off) red[tid] = fminf(red[tid], red[tid + off]);
            __syncthreads();
        }
        if (tid == 0) out[bid] = scores[bid] * red[0];
    }
    if (bid == 511 && tid < NI) {
        int c = counters[tid];
        // 16384*0.05 = 819.2, 16384*0.95 = 15564.8; counts are integers
        out[NM + (size_t)NI * HW + tid] = (c >= 820 && c <= 15564) ? 1.0f : 0.0f;
    }
}

// ===========================================================================
// Guarded fallback (the proven 3-kernel pipeline, verbatim + flag guard).
// Runs only if a fused barrier timed out (bar[2] != 0); recomputes everything
// from the original inputs and overwrites all outputs.
// ===========================================================================
__global__ __launch_bounds__(256) void diou_compm_kernel(
    const unsigned long long* __restrict__ packed, const int* __restrict__ labels,
    float* __restrict__ diouT, float* __restrict__ compm,
    const int* __restrict__ bar) {
    #pragma clang fp contract(off)
    if (bar[2] == 0) return;
    __shared__ unsigned long long colj[WORDS];
    __shared__ float red[NM];
    const int j = blockIdx.x, i = threadIdx.x;
    colj[i] = packed[i * NM + j];
    __syncthreads();
    int inter = 0, si = 0, sj = 0;
    for (int w = 0; w < WORDS; ++w) {
        unsigned long long a = colj[w];
        unsigned long long b = packed[w * NM + i];
        inter += __popcll(a & b);
        sj += __popcll(a);
        si += __popcll(b);
    }
    float d = 0.0f;
    if (j > i && labels[i] == labels[j]) {
        float u = (float)(si + sj - inter);
        d = (float)inter / u;
    }
    diouT[j * NM + i] = d;
    red[i] = d;
    __syncthreads();
    for (int off = 128; off > 0; off >>= 1) {
        if (i < off) red[i] = fmaxf(red[i], red[i + off]);
        __syncthreads();
    }
    if (i == 0) {
        float m = red[0];
        float t = m * m;
        compm[j] = expf(-2.0f * t);
    }
}

template <bool FIRST>
__global__ __launch_bounds__(832, 6) void crf5_kernel(
    const float* __restrict__ feat, const float* __restrict__ scores,
    const float* __restrict__ diouT, const float* __restrict__ compm,
    const float* __restrict__ seg, unsigned long long* __restrict__ packed,
    const float* __restrict__ x, const float* __restrict__ targets,
    unsigned char* __restrict__ state2, float* __restrict__ gplane,
    float* __restrict__ out, int* __restrict__ counters,
    const int* __restrict__ bar) {
    #pragma clang fp contract(off)
    if (bar[2] == 0) return;
    __shared__ float plane[4 * PSZ];
    __shared__ uint32_t stw[2][26 * SR];
    __shared__ int chg;
    const int tid = threadIdx.x, bid = blockIdx.x;
    const int img = bid >> 3, r0 = (bid & 7) * 16;
    const int w0 = r0 - 5;
    const int rel = tid >> 5;
    const int q = tid & 31;
    const int xc = q * 4;
    const int y = w0 + rel;
    const bool inimg = (unsigned)y < 128u;

    if (FIRST) {
        const int wave = tid >> 6, lane = tid & 63;
        const int gw = bid * 13 + wave;
        if (gw < 4096) {
            for (int t = 0; t < 16; ++t) {
                int gwi = gw * 16 + t;
                int i = gwi >> 8, w = gwi & 255;
                float v = seg[(size_t)i * HW + w * 64 + lane];
                unsigned long long m = __ballot(v > 0.5f);
                if (lane == 0) packed[w * NM + i] = m;
            }
        }
        if (bid == 0 && tid < NI + 1) counters[tid] = 0;
    } else {
        if (bid < NM) {
            float* red = plane;
            if (tid < NM) {
                float d = diouT[bid * NM + tid];
                float dd = d * d;
                float dec = expf(-2.0f * dd);
                red[tid] = dec / compm[tid];
            }
            __syncthreads();
            for (int off = 128; off > 0; off >>= 1) {
                if (tid < off) red[tid] = fminf(red[tid], red[tid + off]);
                __syncthreads();
            }
            if (tid == 0) out[bid] = scores[bid] * red[0];
            __syncthreads();
        }
    }

    if (FIRST) {
        const float* fb = feat + (size_t)img * 3 * HW;
        float c0[4], c1[4], c2[4];
        if (inimg) {
            const int pp = y * 128 + xc;
            float4 cv0 = *(const float4*)&fb[pp];
            float4 cv1 = *(const float4*)&fb[HW + pp];
            float4 cv2 = *(const float4*)&fb[2 * HW + pp];
            c0[0]=cv0.x+10.0f; c0[1]=cv0.y+10.0f; c0[2]=cv0.z+10.0f; c0[3]=cv0.w+10.0f;
            c1[0]=cv1.x+10.0f; c1[1]=cv1.y+10.0f; c1[2]=cv1.z+10.0f; c1[3]=cv1.w+10.0f;
            c2[0]=cv2.x+10.0f; c2[1]=cv2.y+10.0f; c2[2]=cv2.z+10.0f; c2[3]=cv2.w+10.0f;
        }
        #pragma unroll
        for (int k = 0; k < 4; ++k) {
            const int dy = (k < 3) ? -1 : 0;
            const int dx = (k < 3) ? (k - 1) : -1;
            float res[4] = {0.0f, 0.0f, 0.0f, 0.0f};
            if (inimg) {
                const int ny = y + dy;
                if ((unsigned)ny < 128u) {
                    #pragma unroll
                    for (int j = 0; j < 4; ++j) {
                        const int nx = xc + j + dx;
                        if ((unsigned)nx < 128u) {
                            const int qq = ny * 128 + nx;
                            float u0 = fb[qq] + 10.0f;
                            float u1 = fb[HW + qq] + 10.0f;
                            float u2 = fb[2 * HW + qq] + 10.0f;
                            float d0 = u0 - c0[j], d1 = u1 - c1[j], d2 = u2 - c2[j];
                            float ss = d0 * d0;
                            ss = ss + d1 * d1;
                            ss = ss + d2 * d2;
                            float color = (-ss) / 0.5f;
                            float sp = (float)(dy * dy + dx * dx) / 1800.0f;
                            res[j] = 3.0f * expf(color - sp);
                        }
                    }
                }
            }
            float4 r4 = make_float4(res[0], res[1], res[2], res[3]);
            *(float4*)&plane[k * PSZ + rel * PR + 4 + xc] = r4;
            *(float4*)&gplane[(((size_t)bid * 4 + k) * 26 + rel) * 128 + xc] = r4;
            if (q == 0)
                *(float4*)&plane[k * PSZ + rel * PR + 0] = make_float4(0, 0, 0, 0);
            if (q == 31)
                *(float4*)&plane[k * PSZ + rel * PR + 132] = make_float4(0, 0, 0, 0);
        }
    } else {
        #pragma unroll
        for (int k = 0; k < 4; ++k) {
            float4 v = *(const float4*)&gplane[(((size_t)bid * 4 + k) * 26 + rel) * 128 + xc];
            *(float4*)&plane[k * PSZ + rel * PR + 4 + xc] = v;
            if (q == 0)
                *(float4*)&plane[k * PSZ + rel * PR + 0] = make_float4(0, 0, 0, 0);
            if (q == 31)
                *(float4*)&plane[k * PSZ + rel * PR + 132] = make_float4(0, 0, 0, 0);
        }
    }
    {
        uint32_t st = 0;
        if (inimg) {
            if (FIRST) {
                const size_t gp = (size_t)img * HW + y * 128 + xc;
                const float4 xv = *(const float4*)(x + gp);
                const float4 tv = *(const float4*)(targets + gp);
                float xs[4] = {xv.x, xv.y, xv.z, xv.w};
                float ts[4] = {tv.x, tv.y, tv.z, tv.w};
                #pragma unroll
                for (int j = 0; j < 4; ++j) {
                    float xt = xs[j] * ts[j];
                    int b1 = (xt > 0.5f) ? 1 : 0;
                    int tb = (ts[j] > 0.5f) ? 1 : 0;
                    st |= (uint32_t)(b1 | ((b1 ^ 1) << 1) | (tb << 2)) << (8 * j);
                }
            } else {
                st = ((const uint32_t*)(state2 + (size_t)img * HW + y * 128))[q];
            }
        }
        stw[0][rel * SR + 1 + q] = st;
        if (!inimg) stw[1][rel * SR + 1 + q] = 0;
        if (q == 0)  { stw[0][rel * SR + 0]  = 0; stw[1][rel * SR + 0]  = 0; }
        if (q == 31) { stw[0][rel * SR + 33] = 0; stw[1][rel * SR + 33] = 0; }
    }
    __syncthreads();

    const bool compute = inimg && (y >= r0 - 4) && (y < r0 + 20);
    const int rbase = rel * PR + 4 + xc;
    const int sbase = rel * SR + 1 + q;
    uint32_t pin[9];
    uint32_t powv = 0;
    bool haveprev = false;
    int cur = sweeps5(plane, stw, &chg, tid, r0, y, compute, rbase, sbase, 0,
                      pin, powv, haveprev);

    int cnt = 0;
    if (inimg && y >= r0 && y < r0 + 16) {
        const uint32_t w = stw[cur][sbase];
        if (FIRST) {
            ((uint32_t*)(state2 + (size_t)img * HW))[y * 32 + q] = w;
        } else {
            float* om = out + NM + (size_t)img * HW;
            *(float4*)(om + y * 128 + xc) =
                make_float4((float)(w & 1), (float)((w >> 8) & 1),
                            (float)((w >> 16) & 1), (float)((w >> 24) & 1));
            cnt = __popc(w & 0x01010101u);
        }
    }

    if (!FIRST) {
        __syncthreads();
        int* cred = (int*)plane;
        cred[tid] = cnt;
        if (tid < 192) cred[832 + tid] = 0;
        __syncthreads();
        for (int off = 512; off > 0; off >>= 1) {
            if (tid < off) cred[tid] += cred[tid + off];
            __syncthreads();
        }
        int* flag = (int*)&stw[0][0];
        if (tid == 0) {
            atomicAdd(&counters[img], cred[0]);
            __threadfence();
            int old = atomicAdd(&counters[NI], 1);
            flag[0] = (old == 511) ? 1 : 0;
        }
        __syncthreads();
        if (flag[0] && tid < NI) {
            int c = atomicAdd(&counters[tid], 0);
            out[NM + (size_t)NI * HW + tid] = (c >= 820 && c <= 15564) ? 1.0f : 0.0f;
        }
    }
}

extern "C" void kernel_launch(void* const* d_in, const int* in_sizes, int n_in,
                              void* d_out, int out_size, void* d_ws, size_t ws_size,
                              hipStream_t stream) {
    const float* seg = (const float*)d_in[0];
    const float* cate_scores = (const float*)d_in[1];
    const float* feat = (const float*)d_in[2];
    const float* x = (const float*)d_in[3];
    const float* targets = (const float*)d_in[4];
    const int* labels = (const int*)d_in[5];
    float* out = (float*)d_out;
    char* ws = (char*)d_ws;

    unsigned char* state2 = (unsigned char*)(ws + OFF_STATE2);
    unsigned long long* packed = (unsigned long long*)(ws + OFF_PACKED);
    float* diouT = (float*)(ws + OFF_DIOUT);
    float* compm = (float*)(ws + OFF_COMPM);
    int* counters = (int*)(ws + OFF_CNT);
    int* bar = (int*)(ws + OFF_BAR);
    float* gplane = (float*)(ws + OFF_GPLANE);

    // Node 0: zero barrier state (required each launch for graph replay)
    init_kernel<<<1, 64, 0, stream>>>(bar);
    // Node 1: fused pipeline with manual device-scope grid barriers
    fused_kernel<<<512, 832, 0, stream>>>(feat, cate_scores, diouT, compm, seg,
                                          packed, labels, x, targets, state2,
                                          out, counters, bar);
    // Nodes 2-4: guarded fallback — no-ops (~2 us each) unless bar[2] was set
    crf5_kernel<true><<<512, 832, 0, stream>>>(feat, cate_scores, diouT, compm,
                                               seg, packed, x, targets, state2,
                                               gplane, out, counters, bar);
    diou_compm_kernel<<<NM, 256, 0, stream>>>(packed, labels, diouT, compm, bar);
    crf5_kernel<false><<<512, 832, 0, stream>>>(feat, cate_scores, diouT, compm,
                                                seg, packed, x, targets, state2,
                                                gplane, out, counters, bar);
}

// Round 4
// 170.403 us; speedup vs baseline: 1001.5235x; 1001.5235x over previous
//
#include <hip/hip_runtime.h>
#include <stdint.h>

#define HW 16384
#define NI 64
#define NM 256
#define WORDS 256

// plane padding: stride 136 floats/row (4 guard cols each side, zeroed)
#define PR 136
// 32-row tile + 10-row halo each side = 52-row window (10 sweeps, no exchange)
#define WROWS 52
#define PSZ (WROWS * PR)          // 7072 floats per plane
// state padding: stride 34 words/row (1 guard word each side, zeroed)
#define SR 34

#define LDS_PLANE_BYTES (4 * PSZ * 4)           // 113152
#define LDS_STW_BYTES   (2 * WROWS * SR * 4)    // 14144
#define LDS_TOTAL       (LDS_PLANE_BYTES + LDS_STW_BYTES + 16)  // 127312 < 160K

// ws layout
#define OFF_PACKED (2u << 20)    // 512 KB bit-packed masks [word][mask]
#define OFF_DIOUT  0x280000u     // 256 KB diou transposed diouT[col][row]
#define OFF_COMPM  0x2C0000u
#define OFF_CNT    0x2C1000u     // 256 per-block partial counts (4 per image)

// ---------------------------------------------------------------------------
// Plane build for one window row (R13-proven sequence, verbatim math).
// ---------------------------------------------------------------------------
__device__ __forceinline__ void build_planes_row(
    const float* __restrict__ fb, float* __restrict__ plane, const int y,
    const int xc, const int wrow, const int q, const bool inimg) {
    #pragma clang fp contract(off)
    float c0[4], c1[4], c2[4];
    if (inimg) {
        const int pp = y * 128 + xc;
        float4 cv0 = *(const float4*)&fb[pp];
        float4 cv1 = *(const float4*)&fb[HW + pp];
        float4 cv2 = *(const float4*)&fb[2 * HW + pp];
        c0[0]=cv0.x+10.0f; c0[1]=cv0.y+10.0f; c0[2]=cv0.z+10.0f; c0[3]=cv0.w+10.0f;
        c1[0]=cv1.x+10.0f; c1[1]=cv1.y+10.0f; c1[2]=cv1.z+10.0f; c1[3]=cv1.w+10.0f;
        c2[0]=cv2.x+10.0f; c2[1]=cv2.y+10.0f; c2[2]=cv2.z+10.0f; c2[3]=cv2.w+10.0f;
    }
    #pragma unroll
    for (int k = 0; k < 4; ++k) {
        const int dy = (k < 3) ? -1 : 0;
        const int dx = (k < 3) ? (k - 1) : -1;
        float res[4] = {0.0f, 0.0f, 0.0f, 0.0f};
        if (inimg) {
            const int ny = y + dy;
            if ((unsigned)ny < 128u) {
                #pragma unroll
                for (int j = 0; j < 4; ++j) {
                    const int nx = xc + j + dx;
                    if ((unsigned)nx < 128u) {
                        const int qq = ny * 128 + nx;
                        float u0 = fb[qq] + 10.0f;
                        float u1 = fb[HW + qq] + 10.0f;
                        float u2 = fb[2 * HW + qq] + 10.0f;
                        float d0 = u0 - c0[j], d1 = u1 - c1[j], d2 = u2 - c2[j];
                        float ss = d0 * d0;
                        ss = ss + d1 * d1;
                        ss = ss + d2 * d2;
                        float color = (-ss) / 0.5f;
                        float sp = (float)(dy * dy + dx * dx) / 1800.0f;
                        res[j] = 3.0f * expf(color - sp);
                    }
                }
            }
        }
        *(float4*)&plane[k * PSZ + wrow * PR + 4 + xc] =
            make_float4(res[0], res[1], res[2], res[3]);
        if (q == 0)
            *(float4*)&plane[k * PSZ + wrow * PR + 0] = make_float4(0, 0, 0, 0);
        if (q == 31)
            *(float4*)&plane[k * PSZ + wrow * PR + 132] = make_float4(0, 0, 0, 0);
    }
}

// ---------------------------------------------------------------------------
// Iter-0 state for one window row (proven). stw0 fully written (0 for OOB),
// stw1 zeroed at OOB slots, guard words of both buffers zeroed.
// ---------------------------------------------------------------------------
__device__ __forceinline__ void stage_init_row(
    const float* __restrict__ x, const float* __restrict__ targets,
    uint32_t* __restrict__ stw0, uint32_t* __restrict__ stw1, const int img,
    const int y, const int wrow, const int q, const int xc, const bool inimg) {
    #pragma clang fp contract(off)
    uint32_t st = 0;
    if (inimg) {
        const size_t gp = (size_t)img * HW + y * 128 + xc;
        const float4 xv = *(const float4*)(x + gp);
        const float4 tv = *(const float4*)(targets + gp);
        float xs[4] = {xv.x, xv.y, xv.z, xv.w};
        float ts[4] = {tv.x, tv.y, tv.z, tv.w};
        #pragma unroll
        for (int j = 0; j < 4; ++j) {
            float xt = xs[j] * ts[j];
            int b1 = (xt > 0.5f) ? 1 : 0;
            int tb = (ts[j] > 0.5f) ? 1 : 0;
            st |= (uint32_t)(b1 | ((b1 ^ 1) << 1) | (tb << 2)) << (8 * j);
        }
    }
    stw0[wrow * SR + 1 + q] = st;
    if (!inimg) stw1[wrow * SR + 1 + q] = 0;
    if (q == 0)  { stw0[wrow * SR + 0]  = 0; stw1[wrow * SR + 0]  = 0; }
    if (q == 31) { stw0[wrow * SR + 33] = 0; stw1[wrow * SR + 33] = 0; }
}

// ---------------------------------------------------------------------------
// One CRF cell update (R13-proven math, verbatim) + value-exact memoization.
// Pure deterministic map: 9 input words (+ fixed per-thread plane slots) ->
// output word, so identical inputs may return the cached output bit-exactly.
// ---------------------------------------------------------------------------
__device__ __forceinline__ uint32_t crf_cell(
    const float* __restrict__ plane, const uint32_t* __restrict__ sw,
    const int rbase, const int sbase, uint32_t (&pin)[9], uint32_t& powv,
    bool& haveprev, uint32_t& wcen_out) {
    #pragma clang fp contract(off)
    const float l45 = 0.7985076962177716f;  // -log(0.45f)
    const float l55 = 0.5978370007556204f;  // -log(0.55f)
    uint32_t in9[9];
    #pragma unroll
    for (int r = 0; r < 3; ++r) {
        const int base = sbase + (r - 1) * SR;
        in9[r * 3 + 0] = sw[base - 1];
        in9[r * 3 + 1] = sw[base];
        in9[r * 3 + 2] = sw[base + 1];
    }
    const uint32_t wcen = in9[4];
    wcen_out = wcen;
    bool same = haveprev;
    #pragma unroll
    for (int m = 0; m < 9; ++m) same = same && (in9[m] == pin[m]);
    if (same) return powv;  // deterministic map on identical inputs — exact

    float lx1r[3][6], lx0r[3][6];
    #pragma unroll
    for (int r = 0; r < 3; ++r) {
        const uint32_t wm = in9[r * 3 + 0];
        const uint32_t wc = in9[r * 3 + 1];
        const uint32_t wp = in9[r * 3 + 2];
        unsigned char b[6];
        b[0] = wm >> 24;
        b[1] = wc & 0xff; b[2] = (wc >> 8) & 0xff;
        b[3] = (wc >> 16) & 0xff; b[4] = wc >> 24;
        b[5] = wp & 0xff;
        #pragma unroll
        for (int m = 0; m < 6; ++m) {
            lx1r[r][m] = (b[m] & 1) ? l55 : l45;
            lx0r[r][m] = (b[m] & 2) ? l55 : l45;
        }
    }
    // kw gather: 7 x b128 + 3 scalars via mirror identity
    float4 p0a = *(const float4*)&plane[0 * PSZ + rbase];
    float4 p1a = *(const float4*)&plane[1 * PSZ + rbase];
    float4 p2a = *(const float4*)&plane[2 * PSZ + rbase];
    float4 p3a = *(const float4*)&plane[3 * PSZ + rbase];
    float4 p0b = *(const float4*)&plane[0 * PSZ + rbase + PR];
    float4 p1b = *(const float4*)&plane[1 * PSZ + rbase + PR];
    float4 p2b = *(const float4*)&plane[2 * PSZ + rbase + PR];
    float s5 = plane[3 * PSZ + rbase + 4];
    float s6 = plane[2 * PSZ + rbase + PR - 1];
    float s8 = plane[0 * PSZ + rbase + PR + 4];
    const float kw[9][4] = {
        {p0a.x, p0a.y, p0a.z, p0a.w},
        {p1a.x, p1a.y, p1a.z, p1a.w},
        {p2a.x, p2a.y, p2a.z, p2a.w},
        {p3a.x, p3a.y, p3a.z, p3a.w},
        {3.0f, 3.0f, 3.0f, 3.0f},
        {p3a.y, p3a.z, p3a.w, s5},
        {s6, p2b.x, p2b.y, p2b.z},
        {p1b.x, p1b.y, p1b.z, p1b.w},
        {p0b.y, p0b.z, p0b.w, s8}};
    float a0[4] = {0.f, 0.f, 0.f, 0.f}, a1[4] = {0.f, 0.f, 0.f, 0.f};
    #pragma unroll
    for (int k = 0; k < 9; ++k) {
        const int r = k / 3, m0 = k % 3;
        #pragma unroll
        for (int j = 0; j < 4; ++j) {
            const float kwv = kw[k][j];
            const float t1 = lx1r[r][j + m0] * kwv;  // mul then add
            const float t0 = lx0r[r][j + m0] * kwv;
            a1[j] = a1[j] + t1;
            a0[j] = a0[j] + t0;
        }
    }
    // epilogue (proven exact sequence)
    uint32_t ow = 0;
    #pragma unroll
    for (int j = 0; j < 4; ++j) {
        const unsigned char sc = (wcen >> (8 * j)) & 0xffu;
        const float tval = (sc & 4) ? 1.0f : 0.0f;
        const float e1 = expf(-a1[j]);
        const float e0 = expf(-a0[j]);
        const float m1 = e1 * tval;
        const float f1 = m1 + 1e-6f;
        const float f0 = e0 + 1e-6f;
        const float den = f0 + f1;
        const float r1 = f1 / den;
        const float r0v = f0 / den;
        const int s1 = (r1 > 0.5f) ? 1 : 0;
        const int s0 = (r0v > 0.5f) ? 1 : 0;
        ow |= (uint32_t)(s1 | (s0 << 1) | (sc & 4)) << (8 * j);
    }
    #pragma unroll
    for (int m = 0; m < 9; ++m) pin[m] = in9[m];
    powv = ow;
    haveprev = true;
    return ow;
}

// ---------------------------------------------------------------------------
// Single-pass CRF: 256 blocks (64 img x 4 tiles of 32 rows), 832 threads,
// 2 window rows per thread, 52-row window = 32 own + 10 halo each side.
// Sweep s computes rows [max(0,r0-9+s), min(128,r0+41-s)) — own rows are
// exact after 10 sweeps with ZERO inter-block exchange (halo shrinks 1/side
// per sweep; OOB rows hold state 0 + kw 0, same proven boundary argument).
// Also: balanced mask pack, mask emission, per-block counts (no atomics).
// ---------------------------------------------------------------------------
__global__ __launch_bounds__(832, 4) void crf10_kernel(
    const float* __restrict__ feat, const float* __restrict__ seg,
    unsigned long long* __restrict__ packed, const float* __restrict__ x,
    const float* __restrict__ targets, float* __restrict__ out,
    int* __restrict__ counters) {
    #pragma clang fp contract(off)
    extern __shared__ char smem[];
    float* plane = (float*)smem;                              // 113152 B
    uint32_t* stw0 = (uint32_t*)(smem + LDS_PLANE_BYTES);     // 7072 B
    uint32_t* stw1 = stw0 + WROWS * SR;                       // 7072 B
    int* chg = (int*)(smem + LDS_PLANE_BYTES + LDS_STW_BYTES);
    uint32_t* const stwb[2] = {stw0, stw1};

    const int tid = threadIdx.x, bid = blockIdx.x;
    const int img = bid >> 2;                 // 4 tiles per image
    const int r0 = (bid & 3) * 32;
    const int relp = tid >> 5;                // 0..25
    const int q = tid & 31;
    const int xc = q * 4;
    const int wrowA = 2 * relp, wrowB = 2 * relp + 1;
    const int yA = r0 - 10 + wrowA, yB = yA + 1;
    const bool inA = (unsigned)yA < 128u, inB = (unsigned)yB < 128u;
    const int rbaseA = wrowA * PR + 4 + xc, rbaseB = wrowB * PR + 4 + xc;
    const int sbaseA = wrowA * SR + 1 + q,  sbaseB = wrowB * SR + 1 + q;
    const float* fb = feat + (size_t)img * 3 * HW;

    // ---- pack, balanced over all 3328 waves (proven ballot body) -----------
    {
        const int wave = tid >> 6, lane = tid & 63;
        const int gw = bid * 13 + wave;          // 0..3327
        for (int gwi = gw; gwi < 65536; gwi += 3328) {
            const int i = gwi >> 8, w = gwi & 255;
            float v = seg[(size_t)i * HW + w * 64 + lane];
            unsigned long long m = __ballot(v > 0.5f);
            if (lane == 0) packed[w * NM + i] = m;
        }
    }

    // ---- planes + iter-0 state for both rows -------------------------------
    build_planes_row(fb, plane, yA, xc, wrowA, q, inA);
    build_planes_row(fb, plane, yB, xc, wrowB, q, inB);
    stage_init_row(x, targets, stw0, stw1, img, yA, wrowA, q, xc, inA);
    stage_init_row(x, targets, stw0, stw1, img, yB, wrowB, q, xc, inB);
    __syncthreads();

    // ---- 10 sweeps, warm memo throughout, block early-exit -----------------
    uint32_t pinA[9], pinB[9];
    uint32_t powvA = 0, powvB = 0;
    bool hpA = false, hpB = false;
    int cur = 0;
    for (int s = 0; s < 10; ++s) {
        if (tid == 0) *chg = 0;
        __syncthreads();
        const int lo = (r0 - 9 + s < 0) ? 0 : r0 - 9 + s;
        const int hi = (r0 + 41 - s > 128) ? 128 : r0 + 41 - s;
        const uint32_t* sw = stwb[cur];
        uint32_t* swn = stwb[cur ^ 1];
        bool changed = false;
        if (yA >= lo && yA < hi) {
            uint32_t wcen;
            uint32_t ow = crf_cell(plane, sw, rbaseA, sbaseA, pinA, powvA, hpA, wcen);
            swn[sbaseA] = ow;
            changed = (ow != wcen);
        }
        if (yB >= lo && yB < hi) {
            uint32_t wcen;
            uint32_t ow = crf_cell(plane, sw, rbaseB, sbaseB, pinB, powvB, hpB, wcen);
            swn[sbaseB] = ow;
            changed = changed || (ow != wcen);
        }
        unsigned long long bal = __ballot(changed);
        if ((tid & 63) == 0 && bal) atomicOr(chg, 1);
        __syncthreads();
        if (*chg == 0) break;  // fixed point: later sweeps identical (exact)
        cur ^= 1;
    }

    // ---- emission: masks + this block's count ------------------------------
    int cnt = 0;
    {
        const uint32_t* swf = stwb[cur];
        float* om = out + NM + (size_t)img * HW;
        if (yA >= r0 && yA < r0 + 32) {
            const uint32_t w = swf[sbaseA];
            *(float4*)(om + yA * 128 + xc) =
                make_float4((float)(w & 1), (float)((w >> 8) & 1),
                            (float)((w >> 16) & 1), (float)((w >> 24) & 1));
            cnt += __popc(w & 0x01010101u);
        }
        if (yB >= r0 && yB < r0 + 32) {
            const uint32_t w = swf[sbaseB];
            *(float4*)(om + yB * 128 + xc) =
                make_float4((float)(w & 1), (float)((w >> 8) & 1),
                            (float)((w >> 16) & 1), (float)((w >> 24) & 1));
            cnt += __popc(w & 0x01010101u);
        }
    }
    __syncthreads();   // before plane reuse as cred
    {
        int* cred = (int*)plane;
        cred[tid] = cnt;
        if (tid < 192) cred[832 + tid] = 0;   // pad to 1024
        __syncthreads();
        for (int off = 512; off > 0; off >>= 1) {
            if (tid < off) cred[tid] += cred[tid + off];
            __syncthreads();
        }
        if (tid == 0) counters[bid] = cred[0];  // per-block partial, no atomics
    }
}

// ---------------------------------------------------------------------------
// NMS diou + compm (proven, verbatim).
// ---------------------------------------------------------------------------
__global__ __launch_bounds__(256) void diou_compm_kernel(
    const unsigned long long* __restrict__ packed, const int* __restrict__ labels,
    float* __restrict__ diouT, float* __restrict__ compm) {
    #pragma clang fp contract(off)
    __shared__ unsigned long long colj[WORDS];
    __shared__ float red[NM];
    const int j = blockIdx.x, i = threadIdx.x;
    colj[i] = packed[i * NM + j];
    __syncthreads();
    int inter = 0, si = 0, sj = 0;
    for (int w = 0; w < WORDS; ++w) {
        unsigned long long a = colj[w];
        unsigned long long b = packed[w * NM + i];
        inter += __popcll(a & b);
        sj += __popcll(a);
        si += __popcll(b);
    }
    float d = 0.0f;
    if (j > i && labels[i] == labels[j]) {
        float u = (float)(si + sj - inter);   // exact integers in f32
        d = (float)inter / u;
    }
    diouT[j * NM + i] = d;
    red[i] = d;
    __syncthreads();
    for (int off = 128; off > 0; off >>= 1) {
        if (i < off) red[i] = fmaxf(red[i], red[i + off]);
        __syncthreads();
    }
    if (i == 0) {
        float m = red[0];
        float t = m * m;
        compm[j] = expf(-2.0f * t);
    }
}

// ---------------------------------------------------------------------------
// coef (proven prologue, verbatim) + valid from per-block partial counts.
// ---------------------------------------------------------------------------
__global__ __launch_bounds__(256) void coef_valid_kernel(
    const float* __restrict__ scores, const float* __restrict__ diouT,
    const float* __restrict__ compm, const int* __restrict__ counters,
    float* __restrict__ out) {
    #pragma clang fp contract(off)
    __shared__ float red[NM];
    const int bid = blockIdx.x, tid = threadIdx.x;
    float d = diouT[bid * NM + tid];
    float dd = d * d;
    float dec = expf(-2.0f * dd);
    red[tid] = dec / compm[tid];
    __syncthreads();
    for (int off = 128; off > 0; off >>= 1) {
        if (tid < off) red[tid] = fminf(red[tid], red[tid + off]);
        __syncthreads();
    }
    if (tid == 0) out[bid] = scores[bid] * red[0];
    if (bid == 0 && tid < NI) {
        int c = counters[4 * tid] + counters[4 * tid + 1] +
                counters[4 * tid + 2] + counters[4 * tid + 3];
        // 16384*0.05 = 819.2, 16384*0.95 = 15564.8; counts are integers
        out[NM + (size_t)NI * HW + tid] = (c >= 820 && c <= 15564) ? 1.0f : 0.0f;
    }
}

extern "C" void kernel_launch(void* const* d_in, const int* in_sizes, int n_in,
                              void* d_out, int out_size, void* d_ws, size_t ws_size,
                              hipStream_t stream) {
    const float* seg = (const float*)d_in[0];
    const float* cate_scores = (const float*)d_in[1];
    const float* feat = (const float*)d_in[2];
    const float* x = (const float*)d_in[3];
    const float* targets = (const float*)d_in[4];
    const int* labels = (const int*)d_in[5];
    float* out = (float*)d_out;
    char* ws = (char*)d_ws;

    unsigned long long* packed = (unsigned long long*)(ws + OFF_PACKED);
    float* diouT = (float*)(ws + OFF_DIOUT);
    float* compm = (float*)(ws + OFF_COMPM);
    int* counters = (int*)(ws + OFF_CNT);

    static bool attr_done = false;
    if (!attr_done) {
        (void)hipFuncSetAttribute((const void*)crf10_kernel,
                                  hipFuncAttributeMaxDynamicSharedMemorySize,
                                  LDS_TOTAL);
        attr_done = true;
    }

    // Node 1: full 10-iter CRF + pack + masks + per-block counts
    crf10_kernel<<<256, 832, LDS_TOTAL, stream>>>(feat, seg, packed, x, targets,
                                                  out, counters);
    // Node 2: NMS diou + compm (needs packed)
    diou_compm_kernel<<<NM, 256, 0, stream>>>(packed, labels, diouT, compm);
    // Node 3: coef + valid (needs diouT/compm/counters)
    coef_valid_kernel<<<NM, 256, 0, stream>>>(cate_scores, diouT, compm,
                                              counters, out);
}

// Round 5
// 167.349 us; speedup vs baseline: 1019.8010x; 1.0182x over previous
//
#include <hip/hip_runtime.h>
#include <stdint.h>

#define HW 16384
#define NI 64
#define NM 256
#define WORDS 256

// plane padding: stride 136 floats/row (4 guard cols each side, zeroed)
#define PR 136
// 32-row tile + 10-row halo each side = 52-row window (10 sweeps, no exchange)
#define WROWS 52
#define PSZ (WROWS * PR)          // 7072 floats per plane
// state padding: stride 34 words/row (1 guard word each side, zeroed)
#define SR 34

#define LDS_PLANE_BYTES (4 * PSZ * 4)           // 113152
#define LDS_STW_BYTES   (2 * WROWS * SR * 4)    // 14144
#define LDS_TOTAL       (LDS_PLANE_BYTES + LDS_STW_BYTES + 64)  // 127360 < 160K

// ws layout
#define OFF_PACKED (2u << 20)    // 512 KB bit-packed masks [word][mask]
#define OFF_DIOUT  0x280000u     // 256 KB diou transposed diouT[col][row]
#define OFF_COMPM  0x2C0000u
#define OFF_CNT    0x2C1000u     // 256 per-block partial counts (4 per image)

// ---------------------------------------------------------------------------
// Plane build for one window row (R13-proven sequence, verbatim math).
// ---------------------------------------------------------------------------
__device__ __forceinline__ void build_planes_row(
    const float* __restrict__ fb, float* __restrict__ plane, const int y,
    const int xc, const int wrow, const int q, const bool inimg) {
    #pragma clang fp contract(off)
    float c0[4], c1[4], c2[4];
    if (inimg) {
        const int pp = y * 128 + xc;
        float4 cv0 = *(const float4*)&fb[pp];
        float4 cv1 = *(const float4*)&fb[HW + pp];
        float4 cv2 = *(const float4*)&fb[2 * HW + pp];
        c0[0]=cv0.x+10.0f; c0[1]=cv0.y+10.0f; c0[2]=cv0.z+10.0f; c0[3]=cv0.w+10.0f;
        c1[0]=cv1.x+10.0f; c1[1]=cv1.y+10.0f; c1[2]=cv1.z+10.0f; c1[3]=cv1.w+10.0f;
        c2[0]=cv2.x+10.0f; c2[1]=cv2.y+10.0f; c2[2]=cv2.z+10.0f; c2[3]=cv2.w+10.0f;
    }
    #pragma unroll
    for (int k = 0; k < 4; ++k) {
        const int dy = (k < 3) ? -1 : 0;
        const int dx = (k < 3) ? (k - 1) : -1;
        float res[4] = {0.0f, 0.0f, 0.0f, 0.0f};
        if (inimg) {
            const int ny = y + dy;
            if ((unsigned)ny < 128u) {
                #pragma unroll
                for (int j = 0; j < 4; ++j) {
                    const int nx = xc + j + dx;
                    if ((unsigned)nx < 128u) {
                        const int qq = ny * 128 + nx;
                        float u0 = fb[qq] + 10.0f;
                        float u1 = fb[HW + qq] + 10.0f;
                        float u2 = fb[2 * HW + qq] + 10.0f;
                        float d0 = u0 - c0[j], d1 = u1 - c1[j], d2 = u2 - c2[j];
                        float ss = d0 * d0;
                        ss = ss + d1 * d1;
                        ss = ss + d2 * d2;
                        float color = (-ss) / 0.5f;
                        float sp = (float)(dy * dy + dx * dx) / 1800.0f;
                        res[j] = 3.0f * expf(color - sp);
                    }
                }
            }
        }
        *(float4*)&plane[k * PSZ + wrow * PR + 4 + xc] =
            make_float4(res[0], res[1], res[2], res[3]);
        if (q == 0)
            *(float4*)&plane[k * PSZ + wrow * PR + 0] = make_float4(0, 0, 0, 0);
        if (q == 31)
            *(float4*)&plane[k * PSZ + wrow * PR + 132] = make_float4(0, 0, 0, 0);
    }
}

// ---------------------------------------------------------------------------
// Iter-0 state for one window row (proven). stw0 fully written (0 for OOB),
// stw1 zeroed at OOB slots, guard words of both buffers zeroed.
// ---------------------------------------------------------------------------
__device__ __forceinline__ void stage_init_row(
    const float* __restrict__ x, const float* __restrict__ targets,
    uint32_t* __restrict__ stw0, uint32_t* __restrict__ stw1, const int img,
    const int y, const int wrow, const int q, const int xc, const bool inimg) {
    #pragma clang fp contract(off)
    uint32_t st = 0;
    if (inimg) {
        const size_t gp = (size_t)img * HW + y * 128 + xc;
        const float4 xv = *(const float4*)(x + gp);
        const float4 tv = *(const float4*)(targets + gp);
        float xs[4] = {xv.x, xv.y, xv.z, xv.w};
        float ts[4] = {tv.x, tv.y, tv.z, tv.w};
        #pragma unroll
        for (int j = 0; j < 4; ++j) {
            float xt = xs[j] * ts[j];
            int b1 = (xt > 0.5f) ? 1 : 0;
            int tb = (ts[j] > 0.5f) ? 1 : 0;
            st |= (uint32_t)(b1 | ((b1 ^ 1) << 1) | (tb << 2)) << (8 * j);
        }
    }
    stw0[wrow * SR + 1 + q] = st;
    if (!inimg) stw1[wrow * SR + 1 + q] = 0;
    if (q == 0)  { stw0[wrow * SR + 0]  = 0; stw1[wrow * SR + 0]  = 0; }
    if (q == 31) { stw0[wrow * SR + 33] = 0; stw1[wrow * SR + 33] = 0; }
}

// ---------------------------------------------------------------------------
// CRF cell core (R13-proven math, verbatim): 9 state words + 9x4 kernel
// weights -> output word. Pure deterministic map; no LDS access.
// ---------------------------------------------------------------------------
__device__ __forceinline__ uint32_t crf_core(const float (&kw)[9][4],
                                             const uint32_t (&in9)[9]) {
    #pragma clang fp contract(off)
    const float l45 = 0.7985076962177716f;  // -log(0.45f)
    const float l55 = 0.5978370007556204f;  // -log(0.55f)
    const uint32_t wcen = in9[4];
    float lx1r[3][6], lx0r[3][6];
    #pragma unroll
    for (int r = 0; r < 3; ++r) {
        const uint32_t wm = in9[r * 3 + 0];
        const uint32_t wc = in9[r * 3 + 1];
        const uint32_t wp = in9[r * 3 + 2];
        unsigned char b[6];
        b[0] = wm >> 24;
        b[1] = wc & 0xff; b[2] = (wc >> 8) & 0xff;
        b[3] = (wc >> 16) & 0xff; b[4] = wc >> 24;
        b[5] = wp & 0xff;
        #pragma unroll
        for (int m = 0; m < 6; ++m) {
            lx1r[r][m] = (b[m] & 1) ? l55 : l45;
            lx0r[r][m] = (b[m] & 2) ? l55 : l45;
        }
    }
    float a0[4] = {0.f, 0.f, 0.f, 0.f}, a1[4] = {0.f, 0.f, 0.f, 0.f};
    #pragma unroll
    for (int k = 0; k < 9; ++k) {
        const int r = k / 3, m0 = k % 3;
        #pragma unroll
        for (int j = 0; j < 4; ++j) {
            const float kwv = kw[k][j];
            const float t1 = lx1r[r][j + m0] * kwv;  // mul then add
            const float t0 = lx0r[r][j + m0] * kwv;
            a1[j] = a1[j] + t1;
            a0[j] = a0[j] + t0;
        }
    }
    // epilogue (proven exact sequence)
    uint32_t ow = 0;
    #pragma unroll
    for (int j = 0; j < 4; ++j) {
        const unsigned char sc = (wcen >> (8 * j)) & 0xffu;
        const float tval = (sc & 4) ? 1.0f : 0.0f;
        const float e1 = expf(-a1[j]);
        const float e0 = expf(-a0[j]);
        const float m1 = e1 * tval;
        const float f1 = m1 + 1e-6f;
        const float f0 = e0 + 1e-6f;
        const float den = f0 + f1;
        const float r1 = f1 / den;
        const float r0v = f0 / den;
        const int s1 = (r1 > 0.5f) ? 1 : 0;
        const int s0 = (r0v > 0.5f) ? 1 : 0;
        ow |= (uint32_t)(s1 | (s0 << 1) | (sc & 4)) << (8 * j);
    }
    return ow;
}

// ---------------------------------------------------------------------------
// Single-pass CRF: 256 blocks (64 img x 4 tiles of 32 rows), 832 threads,
// 2 adjacent window rows per thread, 52-row window. Sweep s computes rows
// [max(0,r0-9+s), min(128,r0+41-s)) — own rows exact after 10 sweeps, zero
// inter-block exchange. kw operands are sweep-invariant: row A's full 9x4
// set + row B's own-row fragments hoisted to REGISTERS after the build
// barrier (rows A,B adjacent -> A's next-row reads are B's own-row values);
// only cell B's row-C fragments stay in LDS (loaded on memo-miss). One
// barrier per sweep via sweep-indexed chg[10] (slot written only in its own
// sweep -> race-free uniform exit). All float sequences verbatim-exact.
// ---------------------------------------------------------------------------
__global__ __launch_bounds__(832, 4) void crf10_kernel(
    const float* __restrict__ feat, const float* __restrict__ seg,
    unsigned long long* __restrict__ packed, const float* __restrict__ x,
    const float* __restrict__ targets, float* __restrict__ out,
    int* __restrict__ counters) {
    #pragma clang fp contract(off)
    extern __shared__ char smem[];
    float* plane = (float*)smem;                              // 113152 B
    uint32_t* stw0 = (uint32_t*)(smem + LDS_PLANE_BYTES);     // 7072 B
    uint32_t* stw1 = stw0 + WROWS * SR;                       // 7072 B
    int* chg = (int*)(smem + LDS_PLANE_BYTES + LDS_STW_BYTES);  // [10]
    uint32_t* const stwb[2] = {stw0, stw1};

    const int tid = threadIdx.x, bid = blockIdx.x;
    const int img = bid >> 2;                 // 4 tiles per image
    const int r0 = (bid & 3) * 32;
    const int relp = tid >> 5;                // 0..25
    const int q = tid & 31;
    const int xc = q * 4;
    const int wrowA = 2 * relp, wrowB = 2 * relp + 1;
    const int yA = r0 - 10 + wrowA, yB = yA + 1;
    const bool inA = (unsigned)yA < 128u, inB = (unsigned)yB < 128u;
    const int rbaseA = wrowA * PR + 4 + xc, rbaseB = wrowB * PR + 4 + xc;
    const int sbaseA = wrowA * SR + 1 + q,  sbaseB = wrowB * SR + 1 + q;
    const float* fb = feat + (size_t)img * 3 * HW;

    // ---- pack, balanced over all 3328 waves (proven ballot body) -----------
    {
        const int wave = tid >> 6, lane = tid & 63;
        const int gw = bid * 13 + wave;          // 0..3327
        for (int gwi = gw; gwi < 65536; gwi += 3328) {
            const int i = gwi >> 8, w = gwi & 255;
            float v = seg[(size_t)i * HW + w * 64 + lane];
            unsigned long long m = __ballot(v > 0.5f);
            if (lane == 0) packed[w * NM + i] = m;
        }
    }

    // ---- planes + iter-0 state for both rows -------------------------------
    build_planes_row(fb, plane, yA, xc, wrowA, q, inA);
    build_planes_row(fb, plane, yB, xc, wrowB, q, inB);
    stage_init_row(x, targets, stw0, stw1, img, yA, wrowA, q, xc, inA);
    stage_init_row(x, targets, stw0, stw1, img, yB, wrowB, q, xc, inB);
    if (tid < 10) chg[tid] = 0;
    __syncthreads();

    // ---- hoist sweep-invariant kw operands to registers --------------------
    // Row A full set (cell A never touches plane LDS again). rbaseB==rbaseA+PR.
    const float4 a_p0 = *(const float4*)&plane[0 * PSZ + rbaseA];
    const float4 a_p1 = *(const float4*)&plane[1 * PSZ + rbaseA];
    const float4 a_p2 = *(const float4*)&plane[2 * PSZ + rbaseA];
    const float4 a_p3 = *(const float4*)&plane[3 * PSZ + rbaseA];
    const float  a_s5 = plane[3 * PSZ + rbaseA + 4];
    const float4 b_p0 = *(const float4*)&plane[0 * PSZ + rbaseB];
    const float4 b_p1 = *(const float4*)&plane[1 * PSZ + rbaseB];
    const float4 b_p2 = *(const float4*)&plane[2 * PSZ + rbaseB];
    const float4 b_p3 = *(const float4*)&plane[3 * PSZ + rbaseB];
    const float  b_s5 = plane[3 * PSZ + rbaseB + 4];
    const float  b_s6 = plane[2 * PSZ + rbaseB - 1];
    const float  b_s8 = plane[0 * PSZ + rbaseB + 4];
    const float kwA[9][4] = {
        {a_p0.x, a_p0.y, a_p0.z, a_p0.w},
        {a_p1.x, a_p1.y, a_p1.z, a_p1.w},
        {a_p2.x, a_p2.y, a_p2.z, a_p2.w},
        {a_p3.x, a_p3.y, a_p3.z, a_p3.w},
        {3.0f, 3.0f, 3.0f, 3.0f},
        {a_p3.y, a_p3.z, a_p3.w, a_s5},
        {b_s6, b_p2.x, b_p2.y, b_p2.z},
        {b_p1.x, b_p1.y, b_p1.z, b_p1.w},
        {b_p0.y, b_p0.z, b_p0.w, b_s8}};

    // ---- 10 sweeps: 1 barrier each, warm memo, block early-exit ------------
    uint32_t pinA[9], pinB[9];
    uint32_t powvA = 0, powvB = 0;
    bool hpA = false, hpB = false;
    int cur = 0;
    for (int s = 0; s < 10; ++s) {
        const int lo = (r0 - 9 + s < 0) ? 0 : r0 - 9 + s;
        const int hi = (r0 + 41 - s > 128) ? 128 : r0 + 41 - s;
        const bool actA = (yA >= lo) && (yA < hi);
        const bool actB = (yB >= lo) && (yB < hi);
        const uint32_t* sw = stwb[cur];
        uint32_t* swn = stwb[cur ^ 1];
        bool changed = false;
        if (actA || actB) {
            // shared middle rows (A,B) of both cells' 3x3 neighborhoods
            const uint32_t ra0 = sw[sbaseA - 1], ra1 = sw[sbaseA], ra2 = sw[sbaseA + 1];
            const uint32_t rb0 = sw[sbaseB - 1], rb1 = sw[sbaseB], rb2 = sw[sbaseB + 1];
            if (actA) {
                const uint32_t in9[9] = {sw[sbaseA - SR - 1], sw[sbaseA - SR],
                                         sw[sbaseA - SR + 1], ra0, ra1, ra2,
                                         rb0, rb1, rb2};
                bool same = hpA;
                #pragma unroll
                for (int m = 0; m < 9; ++m) same = same && (in9[m] == pinA[m]);
                uint32_t ow;
                if (same) {
                    ow = powvA;  // deterministic map on identical inputs — exact
                } else {
                    ow = crf_core(kwA, in9);
                    #pragma unroll
                    for (int m = 0; m < 9; ++m) pinA[m] = in9[m];
                    powvA = ow;
                    hpA = true;
                }
                swn[sbaseA] = ow;
                changed = (ow != ra1);
            }
            if (actB) {
                const uint32_t in9[9] = {ra0, ra1, ra2, rb0, rb1, rb2,
                                         sw[sbaseB + SR - 1], sw[sbaseB + SR],
                                         sw[sbaseB + SR + 1]};
                bool same = hpB;
                #pragma unroll
                for (int m = 0; m < 9; ++m) same = same && (in9[m] == pinB[m]);
                uint32_t ow;
                if (same) {
                    ow = powvB;
                } else {
                    // row-C fragments (sweep-invariant, loaded on miss only)
                    const float4 c_p0 = *(const float4*)&plane[0 * PSZ + rbaseB + PR];
                    const float4 c_p1 = *(const float4*)&plane[1 * PSZ + rbaseB + PR];
                    const float4 c_p2 = *(const float4*)&plane[2 * PSZ + rbaseB + PR];
                    const float  c_s6 = plane[2 * PSZ + rbaseB + PR - 1];
                    const float  c_s8 = plane[0 * PSZ + rbaseB + PR + 4];
                    const float kwB[9][4] = {
                        {b_p0.x, b_p0.y, b_p0.z, b_p0.w},
                        {b_p1.x, b_p1.y, b_p1.z, b_p1.w},
                        {b_p2.x, b_p2.y, b_p2.z, b_p2.w},
                        {b_p3.x, b_p3.y, b_p3.z, b_p3.w},
                        {3.0f, 3.0f, 3.0f, 3.0f},
                        {b_p3.y, b_p3.z, b_p3.w, b_s5},
                        {c_s6, c_p2.x, c_p2.y, c_p2.z},
                        {c_p1.x, c_p1.y, c_p1.z, c_p1.w},
                        {c_p0.y, c_p0.z, c_p0.w, c_s8}};
                    ow = crf_core(kwB, in9);
                    #pragma unroll
                    for (int m = 0; m < 9; ++m) pinB[m] = in9[m];
                    powvB = ow;
                    hpB = true;
                }
                swn[sbaseB] = ow;
                changed = changed || (ow != rb1);
            }
        }
        unsigned long long bal = __ballot(changed);
        if ((tid & 63) == 0 && bal) atomicOr(&chg[s], 1);
        __syncthreads();
        if (chg[s] == 0) break;  // fixed point: later sweeps identical (exact)
        cur ^= 1;
    }

    // ---- emission: masks + this block's count ------------------------------
    int cnt = 0;
    {
        const uint32_t* swf = stwb[cur];
        float* om = out + NM + (size_t)img * HW;
        if (yA >= r0 && yA < r0 + 32) {
            const uint32_t w = swf[sbaseA];
            *(float4*)(om + yA * 128 + xc) =
                make_float4((float)(w & 1), (float)((w >> 8) & 1),
                            (float)((w >> 16) & 1), (float)((w >> 24) & 1));
            cnt += __popc(w & 0x01010101u);
        }
        if (yB >= r0 && yB < r0 + 32) {
            const uint32_t w = swf[sbaseB];
            *(float4*)(om + yB * 128 + xc) =
                make_float4((float)(w & 1), (float)((w >> 8) & 1),
                            (float)((w >> 16) & 1), (float)((w >> 24) & 1));
            cnt += __popc(w & 0x01010101u);
        }
    }
    __syncthreads();   // before plane reuse as cred
    {
        int* cred = (int*)plane;
        cred[tid] = cnt;
        if (tid < 192) cred[832 + tid] = 0;   // pad to 1024
        __syncthreads();
        for (int off = 512; off > 0; off >>= 1) {
            if (tid < off) cred[tid] += cred[tid + off];
            __syncthreads();
        }
        if (tid == 0) counters[bid] = cred[0];  // per-block partial, no atomics
    }
}

// ---------------------------------------------------------------------------
// NMS diou + compm (proven, verbatim).
// ---------------------------------------------------------------------------
__global__ __launch_bounds__(256) void diou_compm_kernel(
    const unsigned long long* __restrict__ packed, const int* __restrict__ labels,
    float* __restrict__ diouT, float* __restrict__ compm) {
    #pragma clang fp contract(off)
    __shared__ unsigned long long colj[WORDS];
    __shared__ float red[NM];
    const int j = blockIdx.x, i = threadIdx.x;
    colj[i] = packed[i * NM + j];
    __syncthreads();
    int inter = 0, si = 0, sj = 0;
    for (int w = 0; w < WORDS; ++w) {
        unsigned long long a = colj[w];
        unsigned long long b = packed[w * NM + i];
        inter += __popcll(a & b);
        sj += __popcll(a);
        si += __popcll(b);
    }
    float d = 0.0f;
    if (j > i && labels[i] == labels[j]) {
        float u = (float)(si + sj - inter);   // exact integers in f32
        d = (float)inter / u;
    }
    diouT[j * NM + i] = d;
    red[i] = d;
    __syncthreads();
    for (int off = 128; off > 0; off >>= 1) {
        if (i < off) red[i] = fmaxf(red[i], red[i + off]);
        __syncthreads();
    }
    if (i == 0) {
        float m = red[0];
        float t = m * m;
        compm[j] = expf(-2.0f * t);
    }
}

// ---------------------------------------------------------------------------
// coef (proven prologue, verbatim) + valid from per-block partial counts.
// ---------------------------------------------------------------------------
__global__ __launch_bounds__(256) void coef_valid_kernel(
    const float* __restrict__ scores, const float* __restrict__ diouT,
    const float* __restrict__ compm, const int* __restrict__ counters,
    float* __restrict__ out) {
    #pragma clang fp contract(off)
    __shared__ float red[NM];
    const int bid = blockIdx.x, tid = threadIdx.x;
    float d = diouT[bid * NM + tid];
    float dd = d * d;
    float dec = expf(-2.0f * dd);
    red[tid] = dec / compm[tid];
    __syncthreads();
    for (int off = 128; off > 0; off >>= 1) {
        if (tid < off) red[tid] = fminf(red[tid], red[tid + off]);
        __syncthreads();
    }
    if (tid == 0) out[bid] = scores[bid] * red[0];
    if (bid == 0 && tid < NI) {
        int c = counters[4 * tid] + counters[4 * tid + 1] +
                counters[4 * tid + 2] + counters[4 * tid + 3];
        // 16384*0.05 = 819.2, 16384*0.95 = 15564.8; counts are integers
        out[NM + (size_t)NI * HW + tid] = (c >= 820 && c <= 15564) ? 1.0f : 0.0f;
    }
}

extern "C" void kernel_launch(void* const* d_in, const int* in_sizes, int n_in,
                              void* d_out, int out_size, void* d_ws, size_t ws_size,
                              hipStream_t stream) {
    const float* seg = (const float*)d_in[0];
    const float* cate_scores = (const float*)d_in[1];
    const float* feat = (const float*)d_in[2];
    const float* x = (const float*)d_in[3];
    const float* targets = (const float*)d_in[4];
    const int* labels = (const int*)d_in[5];
    float* out = (float*)d_out;
    char* ws = (char*)d_ws;

    unsigned long long* packed = (unsigned long long*)(ws + OFF_PACKED);
    float* diouT = (float*)(ws + OFF_DIOUT);
    float* compm = (float*)(ws + OFF_COMPM);
    int* counters = (int*)(ws + OFF_CNT);

    static bool attr_done = false;
    if (!attr_done) {
        (void)hipFuncSetAttribute((const void*)crf10_kernel,
                                  hipFuncAttributeMaxDynamicSharedMemorySize,
                                  LDS_TOTAL);
        attr_done = true;
    }

    // Node 1: full 10-iter CRF + pack + masks + per-block counts
    crf10_kernel<<<256, 832, LDS_TOTAL, stream>>>(feat, seg, packed, x, targets,
                                                  out, counters);
    // Node 2: NMS diou + compm (needs packed)
    diou_compm_kernel<<<NM, 256, 0, stream>>>(packed, labels, diouT, compm);
    // Node 3: coef + valid (needs diouT/compm/counters)
    coef_valid_kernel<<<NM, 256, 0, stream>>>(cate_scores, diouT, compm,
                                              counters, out);
}